// Round 2
// baseline (1280.183 us; speedup 1.0000x reference)
//
#include <hip/hip_runtime.h>
#include <hip/hip_bf16.h>

typedef unsigned short u16;
typedef __attribute__((ext_vector_type(8))) short bf16x8;
typedef __attribute__((ext_vector_type(4))) float f32x4;
typedef __attribute__((ext_vector_type(4))) u16 u16x4;

#define DEV static __device__ __forceinline__

DEV u16 f2bf(float x) {
  unsigned u = __builtin_bit_cast(unsigned, x);
  u += 0x7fffu + ((u >> 16) & 1u);   // round-to-nearest-even (finite values)
  return (u16)(u >> 16);
}

// ---- transpose+convert weights: out_bf16[n*1024+k] = in_f32[k*1024+n], 4 mats ----
__global__ __launch_bounds__(256) void transpose_w(
    const float* __restrict__ w0, const float* __restrict__ w1,
    const float* __restrict__ w2, const float* __restrict__ w3,
    u16* __restrict__ out) {
  __shared__ u16 tile[32][33];
  const int mat = blockIdx.y;
  const float* in = (mat == 0) ? w0 : (mat == 1) ? w1 : (mat == 2) ? w2 : w3;
  u16* o = out + (size_t)mat * 1048576;
  const int bk = ((int)blockIdx.x & 31) << 5;
  const int bn = ((int)blockIdx.x >> 5) << 5;
  const int tx = threadIdx.x & 31, ty = threadIdx.x >> 5;  // ty 0..7
#pragma unroll
  for (int i = 0; i < 32; i += 8)
    tile[ty + i][tx] = f2bf(in[(size_t)(bk + ty + i) * 1024 + bn + tx]);
  __syncthreads();
#pragma unroll
  for (int i = 0; i < 32; i += 8)
    o[(size_t)(bn + ty + i) * 1024 + bk + tx] = tile[tx][ty + i];
}

// ---------- QKV GEMM: Y = X_f32[8192x1024] @ W_bf16 + bias_f32 ----------
// y=0: K-proj -> Kup [B,H,S,64]   y=1: V-proj -> VupT [B,H,64,S]
// y=2: Q-proj (scaled 1/8) -> Qup [B,H,S,64]
__global__ __launch_bounds__(256) void gemm_qkv(
    const float* __restrict__ Xk, const float* __restrict__ Xv,
    const float* __restrict__ Xq, const u16* __restrict__ WTall,
    const float* __restrict__ bK, const float* __restrict__ bV,
    const float* __restrict__ bQ,
    u16* __restrict__ Kup, u16* __restrict__ VupT, u16* __restrict__ Qup) {
  const int mode = blockIdx.y;
  const float* X; const u16* wt; const float* bias;
  if (mode == 0)      { X = Xk; wt = WTall;           bias = bK; }
  else if (mode == 1) { X = Xv; wt = WTall + 1048576; bias = bV; }
  else                { X = Xq; wt = WTall + 2097152; bias = bQ; }

  const int mb = ((int)blockIdx.x >> 4) << 6;   // 128 m-blocks of 64
  const int nb = ((int)blockIdx.x & 15) << 6;   // 16 n-blocks of 64
  const int w = threadIdx.x >> 6, l = threadIdx.x & 63;
  const int ln = l & 15, lg = l >> 4, kg8 = lg << 3;
  const int arow = mb + (w << 4) + ln;

  f32x4 acc[4] = {f32x4{0,0,0,0}, f32x4{0,0,0,0}, f32x4{0,0,0,0}, f32x4{0,0,0,0}};
  const float* xrow = X + (size_t)arow * 1024 + kg8;
  const u16* wrow = wt + (size_t)(nb + ln) * 1024 + kg8;
#pragma unroll 4
  for (int k0 = 0; k0 < 1024; k0 += 32) {
    const f32x4 a0 = *(const f32x4*)(xrow + k0);
    const f32x4 a1 = *(const f32x4*)(xrow + k0 + 4);
    bf16x8 a;
#pragma unroll
    for (int e = 0; e < 4; ++e) {
      a[e] = (short)f2bf(a0[e]);
      a[e + 4] = (short)f2bf(a1[e]);
    }
#pragma unroll
    for (int nt = 0; nt < 4; ++nt) {
      const bf16x8 bb = *(const bf16x8*)(wrow + (size_t)(nt << 4) * 1024 + k0);
      acc[nt] = __builtin_amdgcn_mfma_f32_16x16x32_bf16(a, bb, acc[nt], 0, 0, 0);
    }
  }

  const float scale = (mode == 2) ? 0.125f : 1.0f;
  const int m0 = mb + (w << 4) + (lg << 2);   // C rows: 4*(lane>>4)+r  [m89 layout]
  const int bb_ = m0 >> 10;                   // batch
  const int s0 = m0 & 1023;                   // seq pos
#pragma unroll
  for (int nt = 0; nt < 4; ++nt) {
    const int n = nb + (nt << 4) + ln;        // C col: lane&15
    const float bval = bias[n];
    const int h = n >> 6, dh = n & 63;
    if (mode == 1) {
      u16x4 pk;
#pragma unroll
      for (int r = 0; r < 4; ++r) pk[r] = f2bf(acc[nt][r] + bval);
      *(u16x4*)&VupT[(((size_t)(bb_ * 16 + h) << 6) + dh) * 1024 + s0] = pk;
    } else {
      u16* Y = (mode == 0) ? Kup : Qup;
#pragma unroll
      for (int r = 0; r < 4; ++r)
        Y[(((size_t)(bb_ * 16 + h) << 10) + (s0 + r)) * 64 + dh] =
            f2bf((acc[nt][r] + bval) * scale);
    }
  }
}

// ---------- out-proj GEMM: Out_f32 = Ctx_bf16[8192x1024] @ WoT_bf16 + bo ----------
__global__ __launch_bounds__(256) void gemm_out(
    const u16* __restrict__ Ctx, const u16* __restrict__ WTall,
    const float* __restrict__ bO, float* __restrict__ Out) {
  const u16* wt = WTall + 3145728;
  const int mb = ((int)blockIdx.x >> 4) << 6;
  const int nb = ((int)blockIdx.x & 15) << 6;
  const int w = threadIdx.x >> 6, l = threadIdx.x & 63;
  const int ln = l & 15, lg = l >> 4, kg8 = lg << 3;
  const int arow = mb + (w << 4) + ln;

  f32x4 acc[4] = {f32x4{0,0,0,0}, f32x4{0,0,0,0}, f32x4{0,0,0,0}, f32x4{0,0,0,0}};
  const u16* xrow = Ctx + (size_t)arow * 1024 + kg8;
  const u16* wrow = wt + (size_t)(nb + ln) * 1024 + kg8;
#pragma unroll 4
  for (int k0 = 0; k0 < 1024; k0 += 32) {
    const bf16x8 a = *(const bf16x8*)(xrow + k0);
#pragma unroll
    for (int nt = 0; nt < 4; ++nt) {
      const bf16x8 bb = *(const bf16x8*)(wrow + (size_t)(nt << 4) * 1024 + k0);
      acc[nt] = __builtin_amdgcn_mfma_f32_16x16x32_bf16(a, bb, acc[nt], 0, 0, 0);
    }
  }
  const int m0 = mb + (w << 4) + (lg << 2);
#pragma unroll
  for (int nt = 0; nt < 4; ++nt) {
    const int n = nb + (nt << 4) + ln;
    const float bval = bO[n];
#pragma unroll
    for (int r = 0; r < 4; ++r)
      Out[(size_t)(m0 + r) * 1024 + n] = acc[nt][r] + bval;
  }
}

// ---------- attention: one block = 16 q-rows, all keys, all 16 heads ----------
__global__ __launch_bounds__(256) void attn_kernel(
    const u16* __restrict__ Qup, const u16* __restrict__ Kup,
    const u16* __restrict__ VupT, const int* __restrict__ mask,
    u16* __restrict__ Ctx, float* __restrict__ Amean) {
  __shared__ u16 P_lds[16 * 1024];   // probs, XOR-swizzled rows (stride 2048B)
  __shared__ u16 vt_lds[64 * 128];   // V^T chunk [64 dh][128 keys], swizzled
  __shared__ float red[4][16];

  const int tid = threadIdx.x;
  const int w = tid >> 6, l = tid & 63;
  const int ln = l & 15, lg = l >> 4, kg8 = lg << 3;
  const int b = (int)blockIdx.x >> 6;
  const int qb = ((int)blockIdx.x & 63) << 4;

  // mask bits, loaded ONCE (shared across all 16 heads): bit (t*4+r) for this
  // lane's score element (row = 4*lg+r, key = w*256 + t*16 + ln)
  const int* Mp = mask + ((size_t)b << 20) + ((size_t)qb << 10);
  unsigned long long mbits = 0ull;
#pragma unroll
  for (int t = 0; t < 16; ++t) {
    const int key = (w << 8) + (t << 4) + ln;
#pragma unroll
    for (int r = 0; r < 4; ++r) {
      const int row = (lg << 2) + r;
      if (Mp[((size_t)row << 10) + key] != 0) mbits |= 1ull << ((t << 2) + r);
    }
  }

  f32x4 acc[16];  // attn_mean accumulator (sum of probs over heads)
#pragma unroll
  for (int t = 0; t < 16; ++t) acc[t] = f32x4{0, 0, 0, 0};

  for (int h = 0; h < 16; ++h) {
    const size_t bh = (size_t)(b * 16 + h);
    const u16* Qp = Qup + ((bh << 10) + qb) * 64;
    const u16* Kp = Kup + (bh << 10) * 64;
    const u16* Vp = VupT + (bh << 6) * 1024;

    const bf16x8 qa0 = *(const bf16x8*)&Qp[ln * 64 + kg8];        // dh 0..31
    const bf16x8 qa1 = *(const bf16x8*)&Qp[ln * 64 + 32 + kg8];   // dh 32..63

    // --- QK^T: wave w owns keys [w*256, w*256+256) -> 16 C-tiles in regs
    f32x4 sc[16];
#pragma unroll
    for (int t = 0; t < 16; ++t) {
      const int key = (w << 8) + (t << 4) + ln;
      const bf16x8 kb0 = *(const bf16x8*)&Kp[(size_t)key * 64 + kg8];
      const bf16x8 kb1 = *(const bf16x8*)&Kp[(size_t)key * 64 + 32 + kg8];
      f32x4 c = {0, 0, 0, 0};
      c = __builtin_amdgcn_mfma_f32_16x16x32_bf16(qa0, kb0, c, 0, 0, 0);
      c = __builtin_amdgcn_mfma_f32_16x16x32_bf16(qa1, kb1, c, 0, 0, 0);
      sc[t] = c;
    }

    // --- mask + row max (16 lanes of a row group reduce via shfl_xor)
    float rmax[4] = {-3.0e38f, -3.0e38f, -3.0e38f, -3.0e38f};
#pragma unroll
    for (int t = 0; t < 16; ++t)
#pragma unroll
      for (int r = 0; r < 4; ++r) {
        const float s = ((mbits >> ((t << 2) + r)) & 1ull) ? -3.0e38f : sc[t][r];
        sc[t][r] = s;
        rmax[r] = fmaxf(rmax[r], s);
      }
#pragma unroll
    for (int off = 1; off < 16; off <<= 1) {
#pragma unroll
      for (int r = 0; r < 4; ++r) rmax[r] = fmaxf(rmax[r], __shfl_xor(rmax[r], off));
    }
    if (ln == 0) {
#pragma unroll
      for (int r = 0; r < 4; ++r) red[w][(lg << 2) + r] = rmax[r];
    }
    __syncthreads();
    float mrow[4];
#pragma unroll
    for (int r = 0; r < 4; ++r) {
      const int row = (lg << 2) + r;
      mrow[r] = fmaxf(fmaxf(red[0][row], red[1][row]), fmaxf(red[2][row], red[3][row]));
    }
    // --- exp + row sum
    float rsum[4] = {0, 0, 0, 0};
#pragma unroll
    for (int t = 0; t < 16; ++t)
#pragma unroll
      for (int r = 0; r < 4; ++r) {
        const float p = __expf(sc[t][r] - mrow[r]);
        sc[t][r] = p;
        rsum[r] += p;
      }
#pragma unroll
    for (int off = 1; off < 16; off <<= 1) {
#pragma unroll
      for (int r = 0; r < 4; ++r) rsum[r] += __shfl_xor(rsum[r], off);
    }
    __syncthreads();  // all mrow reads done before red is overwritten
    if (ln == 0) {
#pragma unroll
      for (int r = 0; r < 4; ++r) red[w][(lg << 2) + r] = rsum[r];
    }
    __syncthreads();
    float inv[4];
#pragma unroll
    for (int r = 0; r < 4; ++r) {
      const int row = (lg << 2) + r;
      inv[r] = 1.0f / (red[0][row] + red[1][row] + red[2][row] + red[3][row]);
    }

    // --- normalize, accumulate attn_mean, write P (bf16, swizzled) to LDS
#pragma unroll
    for (int t = 0; t < 16; ++t) {
      const int key = (w << 8) + (t << 4) + ln;
#pragma unroll
      for (int r = 0; r < 4; ++r) {
        const int row = (lg << 2) + r;
        const float p = sc[t][r] * inv[r];
        acc[t][r] += p;
        const int bo_ = ((row << 11) + (key << 1)) ^ ((row & 7) << 4);
        *(u16*)((char*)P_lds + bo_) = f2bf(p);
      }
    }
    __syncthreads();

    // --- PV: loop over 8 key-chunks of 128; wave w owns dh [w*16, w*16+16)
    f32x4 ctx = {0, 0, 0, 0};
#pragma unroll 1
    for (int kc = 0; kc < 8; ++kc) {
#pragma unroll
      for (int i = 0; i < 4; ++i) {   // stage V^T chunk, coalesced 16B/thread
        const int idx = tid + (i << 8);
        const int rowd = idx >> 4;    // dh 0..63
        const int cc = idx & 15;      // 16B chunk in row
        const bf16x8 vv =
            *(const bf16x8*)&Vp[((size_t)rowd << 10) + (kc << 7) + (cc << 3)];
        const int bo_ = ((rowd << 8) + (cc << 4)) ^ ((rowd & 7) << 4);
        *(bf16x8*)((char*)vt_lds + bo_) = vv;
      }
      __syncthreads();
#pragma unroll
      for (int ks = 0; ks < 4; ++ks) {
        const int ak = (kc << 7) + (ks << 5) + kg8;
        const int abyte = ((ln << 11) + (ak << 1)) ^ ((ln & 7) << 4);
        const bf16x8 pa = *(const bf16x8*)((const char*)P_lds + abyte);
        const int brow = (w << 4) + ln;
        const int bbyte = ((brow << 8) + (((ks << 5) + kg8) << 1)) ^ ((brow & 7) << 4);
        const bf16x8 vb = *(const bf16x8*)((const char*)vt_lds + bbyte);
        ctx = __builtin_amdgcn_mfma_f32_16x16x32_bf16(pa, vb, ctx, 0, 0, 0);
      }
      __syncthreads();
    }
    // context write: rows = q, cols = dh (wave's 16)
#pragma unroll
    for (int r = 0; r < 4; ++r) {
      const int row = (lg << 2) + r;
      Ctx[(((size_t)b << 10) + qb + row) * 1024 + (h << 6) + (w << 4) + ln] =
          f2bf(ctx[r]);
    }
  }

  // attn_mean = sum over heads / 16  (fp32 output)
#pragma unroll
  for (int t = 0; t < 16; ++t) {
    const int key = (w << 8) + (t << 4) + ln;
#pragma unroll
    for (int r = 0; r < 4; ++r) {
      const int row = (lg << 2) + r;
      Amean[(((size_t)b << 10) + qb + row) * 1024 + key] = acc[t][r] * 0.0625f;
    }
  }
}

extern "C" void kernel_launch(void* const* d_in, const int* in_sizes, int n_in,
                              void* d_out, int out_size, void* d_ws, size_t ws_size,
                              hipStream_t stream) {
  const float* k_in = (const float*)d_in[0];
  const float* v_in = (const float*)d_in[1];
  const float* q_in = (const float*)d_in[2];
  const int* mask = (const int*)d_in[3];
  const float* Wk = (const float*)d_in[4];
  const float* bk = (const float*)d_in[5];
  const float* Wv = (const float*)d_in[6];
  const float* bv = (const float*)d_in[7];
  const float* Wq = (const float*)d_in[8];
  const float* bq = (const float*)d_in[9];
  const float* Wo = (const float*)d_in[10];
  const float* bo = (const float*)d_in[11];

  float* out = (float*)d_out;                          // [8,1024,1024] f32
  float* amean = out + (size_t)8 * 1024 * 1024;        // [8,1024,1024] f32

  // ws layout (u16 elems): WT 4x1M | Kup 8M | VupT 8M | Qup 8M | Ctx 8M = 72MB
  u16* ws = (u16*)d_ws;
  u16* WT   = ws;
  u16* Kup  = ws + 4194304;
  u16* VupT = ws + 12582912;
  u16* Qup  = ws + 20971520;
  u16* Ctx  = ws + 29360128;

  transpose_w<<<dim3(1024, 4), dim3(256), 0, stream>>>(Wk, Wv, Wq, Wo, WT);
  gemm_qkv<<<dim3(2048, 3), dim3(256), 0, stream>>>(
      k_in, v_in, q_in, WT, bk, bv, bq, Kup, VupT, Qup);
  attn_kernel<<<dim3(512), dim3(256), 0, stream>>>(Qup, Kup, VupT, mask, Ctx, amean);
  gemm_out<<<dim3(2048), dim3(256), 0, stream>>>(Ctx, WT, bo, out);
}

// Round 3
// 657.165 us; speedup vs baseline: 1.9480x; 1.9480x over previous
//
#include <hip/hip_runtime.h>
#include <hip/hip_bf16.h>

typedef unsigned short u16;
typedef unsigned int u32;
typedef __attribute__((ext_vector_type(8))) short bf16x8;
typedef __attribute__((ext_vector_type(4))) float f32x4;
typedef __attribute__((ext_vector_type(4))) u16 u16x4;

#define DEV static __device__ __forceinline__

DEV u16 f2bf(float x) {
  unsigned u = __builtin_bit_cast(unsigned, x);
  u += 0x7fffu + ((u >> 16) & 1u);   // RNE (finite values)
  return (u16)(u >> 16);
}
DEV float bf2f(u16 u) { return __builtin_bit_cast(float, ((unsigned)u) << 16); }

DEV void glds16(const u16* g, u16* l) {
  __builtin_amdgcn_global_load_lds(
      (const __attribute__((address_space(1))) void*)g,
      (__attribute__((address_space(3))) void*)l, 16, 0, 0);
}

// ---- X convert: k,v,q fp32 -> Xb bf16 [3][8388608] (order: k, v, q) ----
__global__ __launch_bounds__(256) void xcvt(
    const float* __restrict__ k, const float* __restrict__ v,
    const float* __restrict__ q, u16* __restrict__ Xb) {
  const size_t i0 = (size_t)blockIdx.x * 256 + threadIdx.x;
  for (size_t t = i0; t < 6291456; t += 524288) {
    const size_t e = t * 4;
    const float* src = (e < 8388608) ? k + e
                     : (e < 16777216) ? v + (e - 8388608)
                     : q + (e - 16777216);
    const f32x4 x = *(const f32x4*)src;
    u16x4 o;
#pragma unroll
    for (int r = 0; r < 4; ++r) o[r] = f2bf(x[r]);
    *(u16x4*)&Xb[e] = o;
  }
}

// ---- transpose+convert weights: out_bf16[n*1024+k] = in_f32[k*1024+n] ----
__global__ __launch_bounds__(256) void transpose_w(
    const float* __restrict__ w0, const float* __restrict__ w1,
    const float* __restrict__ w2, const float* __restrict__ w3,
    u16* __restrict__ out) {
  __shared__ u16 tile[32][33];
  const int mat = blockIdx.y;
  const float* in = (mat == 0) ? w0 : (mat == 1) ? w1 : (mat == 2) ? w2 : w3;
  u16* o = out + (size_t)mat * 1048576;
  const int bk = ((int)blockIdx.x & 31) << 5;
  const int bn = ((int)blockIdx.x >> 5) << 5;
  const int tx = threadIdx.x & 31, ty = threadIdx.x >> 5;
#pragma unroll
  for (int i = 0; i < 32; i += 8)
    tile[ty + i][tx] = f2bf(in[(size_t)(bk + ty + i) * 1024 + bn + tx]);
  __syncthreads();
#pragma unroll
  for (int i = 0; i < 32; i += 8)
    o[(size_t)(bn + ty + i) * 1024 + bk + tx] = tile[tx][ty + i];
}

// ---- m97-style GEMM: 128x128 tile, BK=32, global_load_lds staging ----
// QKV: y=0 K-proj -> Kup [B,H,S,64]; y=1 V -> VupT [B,H,64,S]; y=2 Q(*0.125) -> Qup
__global__ __launch_bounds__(256) void gemm_qkv(
    const u16* __restrict__ Xb, const u16* __restrict__ WTall,
    const float* __restrict__ bK, const float* __restrict__ bV,
    const float* __restrict__ bQ,
    u16* __restrict__ Kup, u16* __restrict__ VupT, u16* __restrict__ Qup) {
  __shared__ u16 As[4096];   // [128][32] linear
  __shared__ u16 Bs[4096];
  const int mode = blockIdx.y;
  const u16* A = Xb + (size_t)mode * 8388608;
  const u16* Bw = WTall + (size_t)mode * 1048576;
  const float* bias = (mode == 0) ? bK : (mode == 1) ? bV : bQ;

  const int tid = threadIdx.x;
  const int w = tid >> 6, l = tid & 63;
  const int ln = l & 15, lg = l >> 4, kg8 = lg << 3;
  const int wr = w >> 1, wc = w & 1;
  const int mb = ((int)blockIdx.x >> 3) << 7;
  const int nb = ((int)blockIdx.x & 7) << 7;

  const int srow = (w << 5) + (l >> 2);       // staging row (inst 0)
  const int sseg = (l & 3) << 3;              // u16 offset in row
  const u16* Ag0 = A + (size_t)(mb + srow) * 1024 + sseg;
  const u16* Bg0 = Bw + (size_t)(nb + srow) * 1024 + sseg;
  u16* Al0 = As + srow * 32 + sseg;           // == w*1024 + l*8 (lane-linear)
  u16* Bl0 = Bs + srow * 32 + sseg;

  f32x4 acc[4][4] = {};
  const int ar = (wr << 6) + ln;
  const int br = (wc << 6) + ln;

  for (int k0 = 0; k0 < 1024; k0 += 32) {
    glds16(Ag0 + k0, Al0);
    glds16(Ag0 + 16384 + k0, Al0 + 512);
    glds16(Bg0 + k0, Bl0);
    glds16(Bg0 + 16384 + k0, Bl0 + 512);
    __syncthreads();
    bf16x8 aa[4], bb[4];
#pragma unroll
    for (int mt = 0; mt < 4; ++mt) aa[mt] = *(const bf16x8*)&As[(ar + (mt << 4)) * 32 + kg8];
#pragma unroll
    for (int nt = 0; nt < 4; ++nt) bb[nt] = *(const bf16x8*)&Bs[(br + (nt << 4)) * 32 + kg8];
#pragma unroll
    for (int mt = 0; mt < 4; ++mt)
#pragma unroll
      for (int nt = 0; nt < 4; ++nt)
        acc[mt][nt] = __builtin_amdgcn_mfma_f32_16x16x32_bf16(aa[mt], bb[nt], acc[mt][nt], 0, 0, 0);
    __syncthreads();
  }

  const float scale = (mode == 2) ? 0.125f : 1.0f;
#pragma unroll
  for (int mt = 0; mt < 4; ++mt) {
    const int m0 = mb + (wr << 6) + (mt << 4) + (lg << 2);
    const int bb_ = m0 >> 10, s0 = m0 & 1023;
#pragma unroll
    for (int nt = 0; nt < 4; ++nt) {
      const int n = nb + (wc << 6) + (nt << 4) + ln;
      const float bval = bias[n];
      const int h = n >> 6, dh = n & 63;
      if (mode == 1) {
        u16x4 pk;
#pragma unroll
        for (int r = 0; r < 4; ++r) pk[r] = f2bf(acc[mt][nt][r] + bval);
        *(u16x4*)&VupT[(((size_t)(bb_ * 16 + h) << 6) + dh) * 1024 + s0] = pk;
      } else {
        u16* Y = (mode == 0) ? Kup : Qup;
#pragma unroll
        for (int r = 0; r < 4; ++r)
          Y[(((size_t)(bb_ * 16 + h) << 10) + s0 + r) * 64 + dh] =
              f2bf((acc[mt][nt][r] + bval) * scale);
      }
    }
  }
}

// ---- out-proj: Out_f32 = Ctx_bf16 @ WoT + bo (same 128x128 structure) ----
__global__ __launch_bounds__(256) void gemm_out(
    const u16* __restrict__ Ctx, const u16* __restrict__ WTall,
    const float* __restrict__ bO, float* __restrict__ Out) {
  __shared__ u16 As[4096];
  __shared__ u16 Bs[4096];
  const u16* Bw = WTall + 3145728;

  const int tid = threadIdx.x;
  const int w = tid >> 6, l = tid & 63;
  const int ln = l & 15, lg = l >> 4, kg8 = lg << 3;
  const int wr = w >> 1, wc = w & 1;
  const int mb = ((int)blockIdx.x >> 3) << 7;
  const int nb = ((int)blockIdx.x & 7) << 7;

  const int srow = (w << 5) + (l >> 2);
  const int sseg = (l & 3) << 3;
  const u16* Ag0 = Ctx + (size_t)(mb + srow) * 1024 + sseg;
  const u16* Bg0 = Bw + (size_t)(nb + srow) * 1024 + sseg;
  u16* Al0 = As + srow * 32 + sseg;
  u16* Bl0 = Bs + srow * 32 + sseg;

  f32x4 acc[4][4] = {};
  const int ar = (wr << 6) + ln;
  const int br = (wc << 6) + ln;

  for (int k0 = 0; k0 < 1024; k0 += 32) {
    glds16(Ag0 + k0, Al0);
    glds16(Ag0 + 16384 + k0, Al0 + 512);
    glds16(Bg0 + k0, Bl0);
    glds16(Bg0 + 16384 + k0, Bl0 + 512);
    __syncthreads();
    bf16x8 aa[4], bb[4];
#pragma unroll
    for (int mt = 0; mt < 4; ++mt) aa[mt] = *(const bf16x8*)&As[(ar + (mt << 4)) * 32 + kg8];
#pragma unroll
    for (int nt = 0; nt < 4; ++nt) bb[nt] = *(const bf16x8*)&Bs[(br + (nt << 4)) * 32 + kg8];
#pragma unroll
    for (int mt = 0; mt < 4; ++mt)
#pragma unroll
      for (int nt = 0; nt < 4; ++nt)
        acc[mt][nt] = __builtin_amdgcn_mfma_f32_16x16x32_bf16(aa[mt], bb[nt], acc[mt][nt], 0, 0, 0);
    __syncthreads();
  }
#pragma unroll
  for (int mt = 0; mt < 4; ++mt) {
    const int m0 = mb + (wr << 6) + (mt << 4) + (lg << 2);
#pragma unroll
    for (int nt = 0; nt < 4; ++nt) {
      const int n = nb + (wc << 6) + (nt << 4) + ln;
      const float bval = bO[n];
#pragma unroll
      for (int r = 0; r < 4; ++r)
        Out[(size_t)(m0 + r) * 1024 + n] = acc[mt][nt][r] + bval;
    }
  }
}

// ---- attention: block = (qtile 16 rows, batch, head-slice of 4 heads) ----
__global__ __launch_bounds__(256) void attn_kernel(
    const u16* __restrict__ Qup, const u16* __restrict__ Kup,
    const u16* __restrict__ VupT, const int* __restrict__ mask,
    u16* __restrict__ Ctx, u16* __restrict__ Pp) {
  __shared__ u16 P_lds[16 * 1024];   // probs, XOR-swizzled rows (stride 2048B)
  __shared__ float red[4][16];

  const int tid = threadIdx.x;
  const int w = tid >> 6, l = tid & 63;
  const int ln = l & 15, lg = l >> 4, kg8 = lg << 3;
  const int qb = (int)blockIdx.x << 4;
  const int b = (int)blockIdx.y;
  const int hs = (int)blockIdx.z;

  // mask bits: bit (t*4+r) for (row = 4*lg+r, key = w*256 + t*16 + ln)
  const int* Mp = mask + ((size_t)b << 20) + ((size_t)qb << 10);
  unsigned long long mbits = 0ull;
#pragma unroll
  for (int t = 0; t < 16; ++t) {
    const int key = (w << 8) + (t << 4) + ln;
#pragma unroll
    for (int r = 0; r < 4; ++r) {
      const int row = (lg << 2) + r;
      if (Mp[((size_t)row << 10) + key] != 0) mbits |= 1ull << ((t << 2) + r);
    }
  }

  f32x4 acc[16];  // partial attn_mean (sum over this slice's 4 heads)
#pragma unroll
  for (int t = 0; t < 16; ++t) acc[t] = f32x4{0, 0, 0, 0};

  for (int hh = 0; hh < 4; ++hh) {
    const int h = (hs << 2) + hh;
    const size_t bh = (size_t)(b * 16 + h);
    const u16* Qp = Qup + ((bh << 10) + qb) * 64;
    const u16* Kp = Kup + (bh << 10) * 64;

    const bf16x8 qa0 = *(const bf16x8*)&Qp[ln * 64 + kg8];
    const bf16x8 qa1 = *(const bf16x8*)&Qp[ln * 64 + 32 + kg8];

    f32x4 sc[16];
#pragma unroll
    for (int t = 0; t < 16; ++t) {
      const int key = (w << 8) + (t << 4) + ln;
      const bf16x8 kb0 = *(const bf16x8*)&Kp[(size_t)key * 64 + kg8];
      const bf16x8 kb1 = *(const bf16x8*)&Kp[(size_t)key * 64 + 32 + kg8];
      f32x4 c = {0, 0, 0, 0};
      c = __builtin_amdgcn_mfma_f32_16x16x32_bf16(qa0, kb0, c, 0, 0, 0);
      c = __builtin_amdgcn_mfma_f32_16x16x32_bf16(qa1, kb1, c, 0, 0, 0);
      sc[t] = c;
    }

    float rmax[4] = {-3.0e38f, -3.0e38f, -3.0e38f, -3.0e38f};
#pragma unroll
    for (int t = 0; t < 16; ++t)
#pragma unroll
      for (int r = 0; r < 4; ++r) {
        const float s = ((mbits >> ((t << 2) + r)) & 1ull) ? -3.0e38f : sc[t][r];
        sc[t][r] = s;
        rmax[r] = fmaxf(rmax[r], s);
      }
#pragma unroll
    for (int off = 1; off < 16; off <<= 1) {
#pragma unroll
      for (int r = 0; r < 4; ++r) rmax[r] = fmaxf(rmax[r], __shfl_xor(rmax[r], off));
    }
    if (ln == 0) {
#pragma unroll
      for (int r = 0; r < 4; ++r) red[w][(lg << 2) + r] = rmax[r];
    }
    __syncthreads();
    float mrow[4];
#pragma unroll
    for (int r = 0; r < 4; ++r) {
      const int row = (lg << 2) + r;
      mrow[r] = fmaxf(fmaxf(red[0][row], red[1][row]), fmaxf(red[2][row], red[3][row]));
    }
    float rsum[4] = {0, 0, 0, 0};
#pragma unroll
    for (int t = 0; t < 16; ++t)
#pragma unroll
      for (int r = 0; r < 4; ++r) {
        const float p = __expf(sc[t][r] - mrow[r]);
        sc[t][r] = p;
        rsum[r] += p;
      }
#pragma unroll
    for (int off = 1; off < 16; off <<= 1) {
#pragma unroll
      for (int r = 0; r < 4; ++r) rsum[r] += __shfl_xor(rsum[r], off);
    }
    __syncthreads();
    if (ln == 0) {
#pragma unroll
      for (int r = 0; r < 4; ++r) red[w][(lg << 2) + r] = rsum[r];
    }
    __syncthreads();
    float inv[4];
#pragma unroll
    for (int r = 0; r < 4; ++r) {
      const int row = (lg << 2) + r;
      inv[r] = 1.0f / (red[0][row] + red[1][row] + red[2][row] + red[3][row]);
    }

#pragma unroll
    for (int t = 0; t < 16; ++t) {
      const int key = (w << 8) + (t << 4) + ln;
#pragma unroll
      for (int r = 0; r < 4; ++r) {
        const int row = (lg << 2) + r;
        const float p = sc[t][r] * inv[r];
        acc[t][r] += p;
        const int bo_ = ((row << 11) + (key << 1)) ^ ((row & 7) << 4);
        *(u16*)((char*)P_lds + bo_) = f2bf(p);
      }
    }
    __syncthreads();

    // PV: A = P from LDS, B = V^T fragments direct from global (L2-resident)
    f32x4 ctx = {0, 0, 0, 0};
    const u16* vrow = VupT + ((bh << 6) + (w << 4) + ln) * 1024;
#pragma unroll
    for (int kk = 0; kk < 32; ++kk) {
      const int abyte = ((ln << 11) + (((kk << 5) + kg8) << 1)) ^ ((ln & 7) << 4);
      const bf16x8 pa = *(const bf16x8*)((const char*)P_lds + abyte);
      const bf16x8 vb = *(const bf16x8*)&vrow[(kk << 5) + kg8];
      ctx = __builtin_amdgcn_mfma_f32_16x16x32_bf16(pa, vb, ctx, 0, 0, 0);
    }
#pragma unroll
    for (int r = 0; r < 4; ++r) {
      const int row = (lg << 2) + r;
      Ctx[(((size_t)b << 10) + qb + row) * 1024 + (h << 6) + (w << 4) + ln] =
          f2bf(ctx[r]);
    }
    __syncthreads();  // P_lds reads done before next head overwrites
  }

  // write bf16 partial-prob plane for this head slice
#pragma unroll
  for (int t = 0; t < 16; ++t) {
    const int key = (w << 8) + (t << 4) + ln;
#pragma unroll
    for (int r = 0; r < 4; ++r) {
      const int row = (lg << 2) + r;
      Pp[(((size_t)(hs * 8 + b) << 10) + qb + row) * 1024 + key] = f2bf(acc[t][r]);
    }
  }
}

// ---- combine: amean = (Pp0+Pp1+Pp2+Pp3)/16, fp32 out ----
__global__ __launch_bounds__(256) void combine(
    const u16* __restrict__ Pp, float* __restrict__ Am) {
  const size_t i = ((size_t)blockIdx.x * 256 + threadIdx.x) * 8;
  f32x4 lo = {0, 0, 0, 0}, hi = {0, 0, 0, 0};
#pragma unroll
  for (int s = 0; s < 4; ++s) {
    const u16x4* p = (const u16x4*)&Pp[(size_t)s * 8388608 + i];
    const u16x4 a = p[0], c = p[1];
#pragma unroll
    for (int r = 0; r < 4; ++r) { lo[r] += bf2f(a[r]); hi[r] += bf2f(c[r]); }
  }
#pragma unroll
  for (int r = 0; r < 4; ++r) { lo[r] *= 0.0625f; hi[r] *= 0.0625f; }
  *(f32x4*)&Am[i] = lo;
  *(f32x4*)&Am[i + 4] = hi;
}

extern "C" void kernel_launch(void* const* d_in, const int* in_sizes, int n_in,
                              void* d_out, int out_size, void* d_ws, size_t ws_size,
                              hipStream_t stream) {
  const float* k_in = (const float*)d_in[0];
  const float* v_in = (const float*)d_in[1];
  const float* q_in = (const float*)d_in[2];
  const int* mask = (const int*)d_in[3];
  const float* Wk = (const float*)d_in[4];
  const float* bk = (const float*)d_in[5];
  const float* Wv = (const float*)d_in[6];
  const float* bv = (const float*)d_in[7];
  const float* Wq = (const float*)d_in[8];
  const float* bq = (const float*)d_in[9];
  const float* Wo = (const float*)d_in[10];
  const float* bo = (const float*)d_in[11];

  float* out = (float*)d_out;                       // [8,1024,1024] f32
  float* amean = out + (size_t)8 * 1024 * 1024;     // [8,1024,1024] f32

  // ws layout (u16 units):
  //  WT   [0, 4M)
  //  U    [4M, 37.75M)  = Xb (24M, dead after gemm_qkv)  ∪  Pp (32M, attn+)
  //  Kup  [37748736, +8M) | VupT [46137344, +8M) | Qup [54525952, +8M)
  //  Ctx  [62914560, +8M)   -> total 71303168 u16 = 142.6 MB
  u16* ws = (u16*)d_ws;
  u16* WT   = ws;
  u16* Xb   = ws + 4194304;
  u16* Pp   = ws + 4194304;
  u16* Kup  = ws + 37748736;
  u16* VupT = ws + 46137344;
  u16* Qup  = ws + 54525952;
  u16* Ctx  = ws + 62914560;

  xcvt<<<2048, 256, 0, stream>>>(k_in, v_in, q_in, Xb);
  transpose_w<<<dim3(1024, 4), dim3(256), 0, stream>>>(Wk, Wv, Wq, Wo, WT);
  gemm_qkv<<<dim3(512, 3), dim3(256), 0, stream>>>(
      Xb, WT, bk, bv, bq, Kup, VupT, Qup);
  attn_kernel<<<dim3(64, 8, 4), dim3(256), 0, stream>>>(
      Qup, Kup, VupT, mask, Ctx, Pp);
  combine<<<4096, 256, 0, stream>>>(Pp, amean);
  gemm_out<<<512, 256, 0, stream>>>(Ctx, WT, bo, out);
}

// Round 4
// 641.270 us; speedup vs baseline: 1.9963x; 1.0248x over previous
//
#include <hip/hip_runtime.h>
#include <hip/hip_bf16.h>

typedef unsigned short u16;
typedef unsigned int u32;
typedef __attribute__((ext_vector_type(8))) short bf16x8;
typedef __attribute__((ext_vector_type(4))) float f32x4;
typedef __attribute__((ext_vector_type(4))) u16 u16x4;

#define DEV static __device__ __forceinline__

DEV u16 f2bf(float x) {
  unsigned u = __builtin_bit_cast(unsigned, x);
  u += 0x7fffu + ((u >> 16) & 1u);   // RNE (finite values)
  return (u16)(u >> 16);
}
DEV float bf2f(u16 u) { return __builtin_bit_cast(float, ((unsigned)u) << 16); }

DEV void glds16(const u16* g, u16* l) {
  __builtin_amdgcn_global_load_lds(
      (const __attribute__((address_space(1))) void*)g,
      (__attribute__((address_space(3))) void*)l, 16, 0, 0);
}

// ---- X convert: k,v,q fp32 -> Xb bf16 [3][8388608] (order: k, v, q) ----
__global__ __launch_bounds__(256) void xcvt(
    const float* __restrict__ k, const float* __restrict__ v,
    const float* __restrict__ q, u16* __restrict__ Xb) {
  const size_t i0 = (size_t)blockIdx.x * 256 + threadIdx.x;
  for (size_t t = i0; t < 6291456; t += 524288) {
    const size_t e = t * 4;
    const float* src = (e < 8388608) ? k + e
                     : (e < 16777216) ? v + (e - 8388608)
                     : q + (e - 16777216);
    const f32x4 x = *(const f32x4*)src;
    u16x4 o;
#pragma unroll
    for (int r = 0; r < 4; ++r) o[r] = f2bf(x[r]);
    *(u16x4*)&Xb[e] = o;
  }
}

// ---- transpose+convert weights: out_bf16[n*1024+k] = in_f32[k*1024+n] ----
__global__ __launch_bounds__(256) void transpose_w(
    const float* __restrict__ w0, const float* __restrict__ w1,
    const float* __restrict__ w2, const float* __restrict__ w3,
    u16* __restrict__ out) {
  __shared__ u16 tile[32][33];
  const int mat = blockIdx.y;
  const float* in = (mat == 0) ? w0 : (mat == 1) ? w1 : (mat == 2) ? w2 : w3;
  u16* o = out + (size_t)mat * 1048576;
  const int bk = ((int)blockIdx.x & 31) << 5;
  const int bn = ((int)blockIdx.x >> 5) << 5;
  const int tx = threadIdx.x & 31, ty = threadIdx.x >> 5;
#pragma unroll
  for (int i = 0; i < 32; i += 8)
    tile[ty + i][tx] = f2bf(in[(size_t)(bk + ty + i) * 1024 + bn + tx]);
  __syncthreads();
#pragma unroll
  for (int i = 0; i < 32; i += 8)
    o[(size_t)(bn + ty + i) * 1024 + bk + tx] = tile[tx][ty + i];
}

// ---- m97-style GEMM: 128x128 tile, BK=32, global_load_lds staging ----
__global__ __launch_bounds__(256) void gemm_qkv(
    const u16* __restrict__ Xb, const u16* __restrict__ WTall,
    const float* __restrict__ bK, const float* __restrict__ bV,
    const float* __restrict__ bQ,
    u16* __restrict__ Kup, u16* __restrict__ VupT, u16* __restrict__ Qup) {
  __shared__ u16 As[4096];   // [128][32] linear
  __shared__ u16 Bs[4096];
  const int mode = blockIdx.y;
  const u16* A = Xb + (size_t)mode * 8388608;
  const u16* Bw = WTall + (size_t)mode * 1048576;
  const float* bias = (mode == 0) ? bK : (mode == 1) ? bV : bQ;

  const int tid = threadIdx.x;
  const int w = tid >> 6, l = tid & 63;
  const int ln = l & 15, lg = l >> 4, kg8 = lg << 3;
  const int wr = w >> 1, wc = w & 1;
  const int mb = ((int)blockIdx.x >> 3) << 7;
  const int nb = ((int)blockIdx.x & 7) << 7;

  const int srow = (w << 5) + (l >> 2);
  const int sseg = (l & 3) << 3;
  const u16* Ag0 = A + (size_t)(mb + srow) * 1024 + sseg;
  const u16* Bg0 = Bw + (size_t)(nb + srow) * 1024 + sseg;
  u16* Al0 = As + srow * 32 + sseg;
  u16* Bl0 = Bs + srow * 32 + sseg;

  f32x4 acc[4][4] = {};
  const int ar = (wr << 6) + ln;
  const int br = (wc << 6) + ln;

  for (int k0 = 0; k0 < 1024; k0 += 32) {
    glds16(Ag0 + k0, Al0);
    glds16(Ag0 + 16384 + k0, Al0 + 512);
    glds16(Bg0 + k0, Bl0);
    glds16(Bg0 + 16384 + k0, Bl0 + 512);
    __syncthreads();
    bf16x8 aa[4], bb[4];
#pragma unroll
    for (int mt = 0; mt < 4; ++mt) aa[mt] = *(const bf16x8*)&As[(ar + (mt << 4)) * 32 + kg8];
#pragma unroll
    for (int nt = 0; nt < 4; ++nt) bb[nt] = *(const bf16x8*)&Bs[(br + (nt << 4)) * 32 + kg8];
#pragma unroll
    for (int mt = 0; mt < 4; ++mt)
#pragma unroll
      for (int nt = 0; nt < 4; ++nt)
        acc[mt][nt] = __builtin_amdgcn_mfma_f32_16x16x32_bf16(aa[mt], bb[nt], acc[mt][nt], 0, 0, 0);
    __syncthreads();
  }

  const float scale = (mode == 2) ? 0.125f : 1.0f;
#pragma unroll
  for (int mt = 0; mt < 4; ++mt) {
    const int m0 = mb + (wr << 6) + (mt << 4) + (lg << 2);
    const int bb_ = m0 >> 10, s0 = m0 & 1023;
#pragma unroll
    for (int nt = 0; nt < 4; ++nt) {
      const int n = nb + (wc << 6) + (nt << 4) + ln;
      const float bval = bias[n];
      const int h = n >> 6, dh = n & 63;
      if (mode == 1) {
        u16x4 pk;
#pragma unroll
        for (int r = 0; r < 4; ++r) pk[r] = f2bf(acc[mt][nt][r] + bval);
        *(u16x4*)&VupT[(((size_t)(bb_ * 16 + h) << 6) + dh) * 1024 + s0] = pk;
      } else {
        u16* Y = (mode == 0) ? Kup : Qup;
#pragma unroll
        for (int r = 0; r < 4; ++r)
          Y[(((size_t)(bb_ * 16 + h) << 10) + s0 + r) * 64 + dh] =
              f2bf((acc[mt][nt][r] + bval) * scale);
      }
    }
  }
}

// ---- out-proj: Out_f32 = Ctx_bf16 @ WoT + bo ----
__global__ __launch_bounds__(256) void gemm_out(
    const u16* __restrict__ Ctx, const u16* __restrict__ WTall,
    const float* __restrict__ bO, float* __restrict__ Out) {
  __shared__ u16 As[4096];
  __shared__ u16 Bs[4096];
  const u16* Bw = WTall + 3145728;

  const int tid = threadIdx.x;
  const int w = tid >> 6, l = tid & 63;
  const int ln = l & 15, lg = l >> 4, kg8 = lg << 3;
  const int wr = w >> 1, wc = w & 1;
  const int mb = ((int)blockIdx.x >> 3) << 7;
  const int nb = ((int)blockIdx.x & 7) << 7;

  const int srow = (w << 5) + (l >> 2);
  const int sseg = (l & 3) << 3;
  const u16* Ag0 = Ctx + (size_t)(mb + srow) * 1024 + sseg;
  const u16* Bg0 = Bw + (size_t)(nb + srow) * 1024 + sseg;
  u16* Al0 = As + srow * 32 + sseg;
  u16* Bl0 = Bs + srow * 32 + sseg;

  f32x4 acc[4][4] = {};
  const int ar = (wr << 6) + ln;
  const int br = (wc << 6) + ln;

  for (int k0 = 0; k0 < 1024; k0 += 32) {
    glds16(Ag0 + k0, Al0);
    glds16(Ag0 + 16384 + k0, Al0 + 512);
    glds16(Bg0 + k0, Bl0);
    glds16(Bg0 + 16384 + k0, Bl0 + 512);
    __syncthreads();
    bf16x8 aa[4], bb[4];
#pragma unroll
    for (int mt = 0; mt < 4; ++mt) aa[mt] = *(const bf16x8*)&As[(ar + (mt << 4)) * 32 + kg8];
#pragma unroll
    for (int nt = 0; nt < 4; ++nt) bb[nt] = *(const bf16x8*)&Bs[(br + (nt << 4)) * 32 + kg8];
#pragma unroll
    for (int mt = 0; mt < 4; ++mt)
#pragma unroll
      for (int nt = 0; nt < 4; ++nt)
        acc[mt][nt] = __builtin_amdgcn_mfma_f32_16x16x32_bf16(aa[mt], bb[nt], acc[mt][nt], 0, 0, 0);
    __syncthreads();
  }
#pragma unroll
  for (int mt = 0; mt < 4; ++mt) {
    const int m0 = mb + (wr << 6) + (mt << 4) + (lg << 2);
#pragma unroll
    for (int nt = 0; nt < 4; ++nt) {
      const int n = nb + (wc << 6) + (nt << 4) + ln;
      const float bval = bO[n];
#pragma unroll
      for (int r = 0; r < 4; ++r)
        Out[(size_t)(m0 + r) * 1024 + n] = acc[mt][nt][r] + bval;
    }
  }
}

// ---- attention: 4096 blocks, XCD-swizzled; block = (qtile, batch, head-PAIR) ----
__global__ __launch_bounds__(256) void attn_kernel(
    const u16* __restrict__ Qup, const u16* __restrict__ Kup,
    const u16* __restrict__ VupT, const int* __restrict__ mask,
    u16* __restrict__ Ctx, u16* __restrict__ Pp) {
  __shared__ u16 P_lds[16 * 1024];   // probs, XOR-swizzled rows (stride 2048B)
  __shared__ float red[4][16];

  const int tid = threadIdx.x;
  const int w = tid >> 6, l = tid & 63;
  const int ln = l & 15, lg = l >> 4, kg8 = lg << 3;

  // XCD-bijective swizzle (nwg=4096, 8 XCDs): XCD x owns swz in [x*512,(x+1)*512)
  // = one head-pair for all batches/qtiles -> K+V pair (4 MB) L2-resident.
  const int bid = (int)blockIdx.x;
  const int swz = ((bid & 7) << 9) | (bid >> 3);
  const int qb = (swz & 63) << 4;
  const int b = (swz >> 6) & 7;
  const int hs = swz >> 9;           // head pair 0..7

  // mask bits: bit (t*4+r) for (row = 4*lg+r, key = w*256 + t*16 + ln)
  const int* Mp = mask + ((size_t)b << 20) + ((size_t)qb << 10);
  unsigned long long mbits = 0ull;
#pragma unroll
  for (int t = 0; t < 16; ++t) {
    const int key = (w << 8) + (t << 4) + ln;
#pragma unroll
    for (int r = 0; r < 4; ++r) {
      const int row = (lg << 2) + r;
      if (Mp[((size_t)row << 10) + key] != 0) mbits |= 1ull << ((t << 2) + r);
    }
  }

  f32x4 acc[16];  // partial attn_mean (sum over this pair's 2 heads)
#pragma unroll
  for (int t = 0; t < 16; ++t) acc[t] = f32x4{0, 0, 0, 0};

#pragma unroll 1
  for (int hh = 0; hh < 2; ++hh) {
    const int h = (hs << 1) + hh;
    const size_t bh = (size_t)(b * 16 + h);
    const u16* Qp = Qup + ((bh << 10) + qb) * 64;
    const u16* Kp = Kup + (bh << 10) * 64;

    const bf16x8 qa0 = *(const bf16x8*)&Qp[ln * 64 + kg8];
    const bf16x8 qa1 = *(const bf16x8*)&Qp[ln * 64 + 32 + kg8];

    // QK^T: wave w owns keys [w*256, w*256+256)
    f32x4 sc[16];
#pragma unroll
    for (int t = 0; t < 16; ++t) {
      const int key = (w << 8) + (t << 4) + ln;
      const bf16x8 kb0 = *(const bf16x8*)&Kp[(size_t)key * 64 + kg8];
      const bf16x8 kb1 = *(const bf16x8*)&Kp[(size_t)key * 64 + 32 + kg8];
      f32x4 c = {0, 0, 0, 0};
      c = __builtin_amdgcn_mfma_f32_16x16x32_bf16(qa0, kb0, c, 0, 0, 0);
      c = __builtin_amdgcn_mfma_f32_16x16x32_bf16(qa1, kb1, c, 0, 0, 0);
      sc[t] = c;
    }

    float rmax[4] = {-3.0e38f, -3.0e38f, -3.0e38f, -3.0e38f};
#pragma unroll
    for (int t = 0; t < 16; ++t)
#pragma unroll
      for (int r = 0; r < 4; ++r) {
        const float s = ((mbits >> ((t << 2) + r)) & 1ull) ? -3.0e38f : sc[t][r];
        sc[t][r] = s;
        rmax[r] = fmaxf(rmax[r], s);
      }
#pragma unroll
    for (int off = 1; off < 16; off <<= 1) {
#pragma unroll
      for (int r = 0; r < 4; ++r) rmax[r] = fmaxf(rmax[r], __shfl_xor(rmax[r], off));
    }
    if (ln == 0) {
#pragma unroll
      for (int r = 0; r < 4; ++r) red[w][(lg << 2) + r] = rmax[r];
    }
    __syncthreads();
    float mrow[4];
#pragma unroll
    for (int r = 0; r < 4; ++r) {
      const int row = (lg << 2) + r;
      mrow[r] = fmaxf(fmaxf(red[0][row], red[1][row]), fmaxf(red[2][row], red[3][row]));
    }
    float rsum[4] = {0, 0, 0, 0};
#pragma unroll
    for (int t = 0; t < 16; ++t)
#pragma unroll
      for (int r = 0; r < 4; ++r) {
        const float p = __expf(sc[t][r] - mrow[r]);
        sc[t][r] = p;
        rsum[r] += p;
      }
#pragma unroll
    for (int off = 1; off < 16; off <<= 1) {
#pragma unroll
      for (int r = 0; r < 4; ++r) rsum[r] += __shfl_xor(rsum[r], off);
    }
    __syncthreads();
    if (ln == 0) {
#pragma unroll
      for (int r = 0; r < 4; ++r) red[w][(lg << 2) + r] = rsum[r];
    }
    __syncthreads();
    float inv[4];
#pragma unroll
    for (int r = 0; r < 4; ++r) {
      const int row = (lg << 2) + r;
      inv[r] = 1.0f / (red[0][row] + red[1][row] + red[2][row] + red[3][row]);
    }

#pragma unroll
    for (int t = 0; t < 16; ++t) {
      const int key = (w << 8) + (t << 4) + ln;
#pragma unroll
      for (int r = 0; r < 4; ++r) {
        const int row = (lg << 2) + r;
        const float p = sc[t][r] * inv[r];
        acc[t][r] += p;
        const int bo_ = ((row << 11) + (key << 1)) ^ ((row & 7) << 4);
        *(u16*)((char*)P_lds + bo_) = f2bf(p);
      }
    }
    __syncthreads();

    // PV: A = P from LDS, B = V^T from global (L2-resident via XCD swizzle).
    // Two independent accumulators break the MFMA dependency chain.
    f32x4 c0 = {0, 0, 0, 0}, c1 = {0, 0, 0, 0};
    const u16* vrow = VupT + ((bh << 6) + (w << 4) + ln) * 1024;
#pragma unroll
    for (int kk = 0; kk < 32; kk += 2) {
      const int a0 = ((ln << 11) + (((kk << 5) + kg8) << 1)) ^ ((ln & 7) << 4);
      const int a1 = ((ln << 11) + ((((kk + 1) << 5) + kg8) << 1)) ^ ((ln & 7) << 4);
      const bf16x8 pa0 = *(const bf16x8*)((const char*)P_lds + a0);
      const bf16x8 pa1 = *(const bf16x8*)((const char*)P_lds + a1);
      const bf16x8 vb0 = *(const bf16x8*)&vrow[(kk << 5) + kg8];
      const bf16x8 vb1 = *(const bf16x8*)&vrow[((kk + 1) << 5) + kg8];
      c0 = __builtin_amdgcn_mfma_f32_16x16x32_bf16(pa0, vb0, c0, 0, 0, 0);
      c1 = __builtin_amdgcn_mfma_f32_16x16x32_bf16(pa1, vb1, c1, 0, 0, 0);
    }
#pragma unroll
    for (int r = 0; r < 4; ++r) {
      const int row = (lg << 2) + r;
      Ctx[(((size_t)b << 10) + qb + row) * 1024 + (h << 6) + (w << 4) + ln] =
          f2bf(c0[r] + c1[r]);
    }
    __syncthreads();  // P_lds reads done before it is overwritten
  }

  // stage acc (pair-sum of probs) into P_lds, then coalesced plane write
#pragma unroll
  for (int t = 0; t < 16; ++t) {
    const int key = (w << 8) + (t << 4) + ln;
#pragma unroll
    for (int r = 0; r < 4; ++r) {
      const int row = (lg << 2) + r;
      const int bo_ = ((row << 11) + (key << 1)) ^ ((row & 7) << 4);
      *(u16*)((char*)P_lds + bo_) = f2bf(acc[t][r]);
    }
  }
  __syncthreads();
  {
    const int row = tid >> 4;
    u16* Pg = Pp + (((size_t)(hs * 8 + b) << 10) + qb + row) * 1024;
#pragma unroll
    for (int i = 0; i < 8; ++i) {
      const int chunk = (tid & 15) + (i << 4);
      const int bo_ = ((row << 11) + (chunk << 4)) ^ ((row & 7) << 4);
      *(bf16x8*)&Pg[chunk << 3] = *(const bf16x8*)((const char*)P_lds + bo_);
    }
  }
}

// ---- combine: amean = sum of 8 pair-planes / 16, fp32 out ----
__global__ __launch_bounds__(256) void combine(
    const u16* __restrict__ Pp, float* __restrict__ Am) {
  const size_t i = ((size_t)blockIdx.x * 256 + threadIdx.x) * 8;
  float s[8] = {0, 0, 0, 0, 0, 0, 0, 0};
#pragma unroll
  for (int p = 0; p < 8; ++p) {
    const u16x4* q = (const u16x4*)&Pp[(size_t)p * 8388608 + i];
    const u16x4 a = q[0], c = q[1];
#pragma unroll
    for (int r = 0; r < 4; ++r) { s[r] += bf2f(a[r]); s[r + 4] += bf2f(c[r]); }
  }
  f32x4 lo, hi;
#pragma unroll
  for (int r = 0; r < 4; ++r) { lo[r] = s[r] * 0.0625f; hi[r] = s[r + 4] * 0.0625f; }
  *(f32x4*)&Am[i] = lo;
  *(f32x4*)&Am[i + 4] = hi;
}

extern "C" void kernel_launch(void* const* d_in, const int* in_sizes, int n_in,
                              void* d_out, int out_size, void* d_ws, size_t ws_size,
                              hipStream_t stream) {
  const float* k_in = (const float*)d_in[0];
  const float* v_in = (const float*)d_in[1];
  const float* q_in = (const float*)d_in[2];
  const int* mask = (const int*)d_in[3];
  const float* Wk = (const float*)d_in[4];
  const float* bk = (const float*)d_in[5];
  const float* Wv = (const float*)d_in[6];
  const float* bv = (const float*)d_in[7];
  const float* Wq = (const float*)d_in[8];
  const float* bq = (const float*)d_in[9];
  const float* Wo = (const float*)d_in[10];
  const float* bo = (const float*)d_in[11];

  float* out = (float*)d_out;                       // [8,1024,1024] f32
  float* amean = out + (size_t)8 * 1024 * 1024;     // [8,1024,1024] f32

  // ws layout (u16 units):
  //  WT [0, 4M) | Pp [4M, 71303168) (8 planes; Xb 24M aliased at start, dead
  //  before attn) | Kup | VupT | Qup | Ctx  -> total 104857600 u16 = 210 MB
  u16* ws = (u16*)d_ws;
  u16* WT   = ws;
  u16* Xb   = ws + 4194304;
  u16* Pp   = ws + 4194304;
  u16* Kup  = ws + 71303168;
  u16* VupT = ws + 79691776;
  u16* Qup  = ws + 88080384;
  u16* Ctx  = ws + 96468992;

  xcvt<<<2048, 256, 0, stream>>>(k_in, v_in, q_in, Xb);
  transpose_w<<<dim3(1024, 4), dim3(256), 0, stream>>>(Wk, Wv, Wq, Wo, WT);
  gemm_qkv<<<dim3(512, 3), dim3(256), 0, stream>>>(
      Xb, WT, bk, bv, bq, Kup, VupT, Qup);
  attn_kernel<<<dim3(4096), dim3(256), 0, stream>>>(
      Qup, Kup, VupT, mask, Ctx, Pp);
  combine<<<4096, 256, 0, stream>>>(Pp, amean);
  gemm_out<<<512, 256, 0, stream>>>(Ctx, WT, bo, out);
}